// Round 9
// baseline (18.914 us; speedup 1.0000x reference)
//
#include <hip/hip_runtime.h>
#include <math.h>

#define NC 5
#define NBASIS (NC + 1)
#define EPSF 1e-10f
#define BIGF 1e10f

struct BMat { float b[2 * NC][NBASIS]; };

// Reproduce numpy.linalg.svd(L)'s null-space basis (rows nC-1.. of Vt).
// LAPACK dgesdd (M=4 << N=10) LQ path: basis col c = H1 H2 H3 H4 e_{M+c}.
static BMat compute_basis() {
    const int m = NC - 1;      // 4
    const int n = 2 * NC;      // 10
    double A[NC - 1][2 * NC];
    for (int r = 0; r < m; ++r)
        for (int c = 0; c < n; ++c) A[r][c] = 0.0;
    for (int k = 1; k < NC; ++k) {
        double xk = (double)k / (double)NC;
        int i = k - 1;
        A[i][2 * i]     = xk;   A[i][2 * i + 1] = 1.0;
        A[i][2 * i + 2] = -xk;  A[i][2 * i + 3] = -1.0;
    }
    double tau[NC - 1];
    for (int i = 0; i < m; ++i) {
        double alpha = A[i][i];
        double xs = 0.0;
        for (int j = i + 1; j < n; ++j) xs += A[i][j] * A[i][j];
        double xnorm = sqrt(xs);
        if (xnorm == 0.0) { tau[i] = 0.0; continue; }
        double beta = (alpha >= 0.0 ? -1.0 : 1.0) * sqrt(alpha * alpha + xs);
        tau[i] = (beta - alpha) / beta;
        double inv = 1.0 / (alpha - beta);
        for (int j = i + 1; j < n; ++j) A[i][j] *= inv;
        A[i][i] = beta;
        for (int r = i + 1; r < m; ++r) {
            double dot = A[r][i];
            for (int j = i + 1; j < n; ++j) dot += A[r][j] * A[i][j];
            dot *= tau[i];
            A[r][i] -= dot;
            for (int j = i + 1; j < n; ++j) A[r][j] -= dot * A[i][j];
        }
    }
    BMat B;
    for (int c = 0; c < NBASIS; ++c) {
        double v[2 * NC];
        for (int r = 0; r < n; ++r) v[r] = 0.0;
        v[m + c] = 1.0;
        for (int i = m - 1; i >= 0; --i) {
            double dot = v[i];
            for (int j = i + 1; j < n; ++j) dot += A[i][j] * v[j];
            dot *= tau[i];
            v[i] -= dot;
            for (int j = i + 1; j < n; ++j) v[j] -= dot * A[i][j];
        }
        for (int r = 0; r < n; ++r) B.b[r][c] = (float)v[r];
    }
    return B;
}

// Reference-faithful decision logic (verified rounds 2-7) used ONLY to classify
// segment midpoints: kind 0=no-cross, 1=stuck-at-left-knot, 2=cross->jf
__device__ __forceinline__ void classify_pt(
    float ym, int c, float a, float b, float kL, float kR,
    float vL, float vR, const float* tR, int& kind, int& jf)
{
#pragma clang fp contract(off)
    float v = a * ym + b;
    bool pos = (v >= 0.0f);
    float xb = pos ? kR : kL;
    bool at_edge = pos ? (c == NC - 1) : (c == 0);
    float vb = pos ? vR : vL;
    bool vok = fabsf(v) > EPSF;
    float vs = vok ? v : 1.0f;
    float ratio = vb / vs;
    bool aok = fabsf(a) > EPSF;
    float as = aok ? a : 1.0f;
    float t0 = aok ? (logf(ratio > EPSF ? ratio : 1.0f) / as)
                   : ((xb - ym) / vs);
    bool valid = vok && (ratio > EPSF) && (!at_edge);
    if (!valid) t0 = BIGF;
    if (!(t0 < 1.0f)) { kind = 0; jf = c; return; }
    if (!pos)         { kind = 1; jf = c; return; }
    kind = 2;
    int j = c + 1; float T = t0;
    while (j < NC - 1 && (T + tR[j] < 1.0f)) { T += tR[j]; ++j; }
    jf = j;
}

// Fused kernel (R7 structure — best measured). Global x loads issued FIRST;
// build parallelized (phase4: one lane per (cell,segment) = 25 lanes).
// Per segment s=c*5+g: L = log|y-y0|; z = S0 + S1*y + S2*exp(S3*L + S4);
// lj = D0 + D1*L (output affine + ljadd pre-folded).
// THIS ROUND'S A/B: plain float4 stores (no nontemporal) — let L2/L3 absorb
// the 32 MB output and write back after kernel end.
__global__ __launch_bounds__(256) void cpab_fused(
    const float* __restrict__ x, const float* __restrict__ theta,
    const float* __restrict__ pa, const float* __restrict__ pb,
    const float* __restrict__ pc, const float* __restrict__ pd,
    float* __restrict__ out, int N, BMat Bm)
{
#pragma clang fp contract(off)
    __shared__ float sA[2 * NC];
    __shared__ float sa[NC], sb[NC], svL[NC], svR[NC], stR[NC], sljR[NC];
    __shared__ float4 sThr[NC];
    __shared__ float4 sS[NC * 5];
    __shared__ float4 sD[NC * 5];
    __shared__ float sAff[4];
    int tid = threadIdx.x;

    // ---- issue global loads first: latency hides under the table build ----
    int nv = N >> 2;
    int base = blockIdx.x * 512 + tid;      // block tile: 512 float4s
    bool ok0 = base < nv;
    bool ok1 = (base + 256) < nv;
    float4 xv0, xv1;
    const float4* x4 = (const float4*)x;
    if (ok0) xv0 = x4[base];
    if (ok1) xv1 = x4[base + 256];

    // ---- phase 1: A = B*theta, affine scalars ----
    if (tid < 2 * NC) {
        float acc = 0.0f;
#pragma unroll
        for (int j = 0; j < NBASIS; ++j) acc += Bm.b[tid][j] * theta[j];
        sA[tid] = acc;
    }
    if (tid == 2 * NC) {
        sAff[0] = pa[0]; sAff[1] = pb[0]; sAff[2] = pc[0]; sAff[3] = pd[0];
    }
    __syncthreads();

    // ---- phase 2: per-cell primitives (bit-identical to ref) ----
    if (tid < NC) {
        int m = tid;
        float a = sA[2 * m], b = sA[2 * m + 1];
        float kL = (float)m / 5.0f, kR = (float)(m + 1) / 5.0f;
        float vL = a * kL + b, vR = a * kR + b;
        bool vok = fabsf(vL) > EPSF;
        float vs = vok ? vL : 1.0f;
        float ratio = vR / vs;
        bool aok = fabsf(a) > EPSF;
        float as = aok ? a : 1.0f;
        float t = aok ? (logf(ratio > EPSF ? ratio : 1.0f) / as)
                      : ((kR - kL) / vs);
        bool valid = vok && (ratio > EPSF) && (m != NC - 1) && (vL >= 0.0f);
        sa[m] = a; sb[m] = b; svL[m] = vL; svR[m] = vR;
        stR[m]  = valid ? t : BIGF;
        sljR[m] = valid ? (a * t) : 0.0f;
    }
    __syncthreads();

    // ---- phase 3: per-cell segment thresholds ----
    if (tid < NC) {
        int c = tid;
        float a = sa[c], b = sb[c];
        float kL = (float)c / 5.0f, kR = (float)(c + 1) / 5.0f;
        float vL = svL[c], vR = svR[c];
        bool aok = fabsf(a) > EPSF;
        float cand[4];
        int ncand = 0;
        if (aok) {
            if (c > 0 && vL < -EPSF) cand[ncand++] = (vL * expf(-a) - b) / a;
            float sum = 0.0f;
            for (int j = c; j <= NC - 2; ++j) {
                if (j > c) {
                    if (stR[j] >= 0.5f * BIGF) break;
                    sum += stR[j];
                    if (sum >= 1.0f) break;
                }
                float tau = 1.0f - sum;
                if (ncand < 4) cand[ncand++] = (vR * expf(-a * tau) - b) / a;
            }
        } else {
            if (c > 0 && b < -EPSF) cand[ncand++] = kL - b;
            if (b > EPSF) {
                float sum = 0.0f;
                for (int j = c; j <= NC - 2; ++j) {
                    if (j > c) {
                        if (stR[j] >= 0.5f * BIGF) break;
                        sum += stR[j];
                        if (sum >= 1.0f) break;
                    }
                    float tau = 1.0f - sum;
                    if (ncand < 4) cand[ncand++] = kR - b * tau;
                }
            }
        }
        for (int i = ncand; i < 4; ++i) cand[i] = 1e30f;
        for (int i = 1; i < 4; ++i) {
            float key = cand[i]; int j = i - 1;
            while (j >= 0 && cand[j] > key) { cand[j + 1] = cand[j]; --j; }
            cand[j + 1] = key;
        }
        sThr[c] = make_float4(cand[0], cand[1], cand[2], cand[3]);
    }
    __syncthreads();

    // ---- phase 4: coefficients, one lane per (cell,segment) = 25 lanes ----
    if (tid < NC * 5) {
        int c = tid / 5, g = tid % 5;
        float a = sa[c], b = sb[c];
        float kL = (float)c / 5.0f, kR = (float)(c + 1) / 5.0f;
        float vL = svL[c], vR = svR[c];
        bool aok = fabsf(a) > EPSF;
        const float* thr = (const float*)&sThr[c];
        float lo = (g == 0) ? -1e30f : thr[g - 1];
        float hi = (g == 4) ?  1e30f : thr[g];
        float lo2 = fmaxf(lo, kL), hi2 = fminf(hi, kR);
        float S0 = 0, S1 = 0, S2 = 0, S3 = 0, S4 = 0, D0 = 0, D1 = 0;
        float aeC = aok ? a : 1e-7f;
        float La  = logf(fabsf(aeC));
        float y0  = -b / aeC;
        if (lo2 < hi2) {
            float ym = 0.5f * (lo2 + hi2);
            int kind, jf;
            classify_pt(ym, c, a, b, kL, kR, vL, vR, stR, kind, jf);
            if (kind == 0) {
                float G = aok ? (expm1f(a) / a) : 1.0f;
                S0 = b * G; S1 = 1.0f + a * G;
                D0 = a;
            } else if (kind == 1) {
                S0 = kL;
                D0 = logf(fabsf(vL)) - La; D1 = -1.0f;
            } else {
                float PTd = 0.0f, PLd = 0.0f;
                for (int m2 = c + 1; m2 < jf; ++m2) { PTd += stR[m2]; PLd += sljR[m2]; }
                float aj  = sa[jf];
                float aeJ = (fabsf(aj) > EPSF) ? aj : 1e-7f;
                float Q   = svL[jf] / aeJ;
                float LVR = logf(vR);       // vR > 0 in cross regime
                S3 = aeJ / aeC;
                S4 = S3 * (La - LVR) - aeJ * PTd;
                S2 = Q * expf(aeJ);
                S0 = (float)jf / 5.0f - Q;  // kL of final cell, minus Q
                D1 = S3 - 1.0f;
                D0 = (1.0f - S3) * LVR + PLd + aj * (1.0f - PTd) + (S3 - 1.0f) * La;
            }
        }
        float affa = sAff[0], affc = sAff[2], affd = sAff[3];
        float ljadd = logf(affa * affc);   // exactly 0 for identity affine
        sS[tid] = make_float4(affc * S0 + affd, affc * S1, affc * S2, S3);
        sD[tid] = make_float4(S4, D0 + ljadd, D1, y0);
    }
    __syncthreads();

    // ---- streaming eval ----
    float affa = sAff[0], affb = sAff[1];
    float4* oz = (float4*)out;
    float4* ol = (float4*)(out + N);

    float xin[8];
    xin[0] = xv0.x; xin[1] = xv0.y; xin[2] = xv0.z; xin[3] = xv0.w;
    xin[4] = xv1.x; xin[5] = xv1.y; xin[6] = xv1.z; xin[7] = xv1.w;
    float zi[8], li[8];
#pragma unroll
    for (int q = 0; q < 8; ++q) {
        float y = affa * xin[q] + affb;        // mul+add order matches ref
        int c = (int)floorf(y * 5.0f);
        c = c < 0 ? 0 : (c > 4 ? 4 : c);
        float4 th = sThr[c];
        int cnt = (y > th.x) + (y > th.y) + (y > th.z) + (y > th.w);
        int s = c * 5 + cnt;
        float4 S = sS[s];
        float4 D = sD[s];
        float L = __logf(fmaxf(fabsf(y - D.w), 1e-37f));
        float E = __expf(fmaf(S.w, L, D.x));
        zi[q] = fmaf(S.z, E, fmaf(S.y, y, S.x));
        li[q] = fmaf(D.z, L, D.y);
    }
    if (ok0) {
        oz[base] = make_float4(zi[0], zi[1], zi[2], zi[3]);
        ol[base] = make_float4(li[0], li[1], li[2], li[3]);
    }
    if (ok1) {
        oz[base + 256] = make_float4(zi[4], zi[5], zi[6], zi[7]);
        ol[base + 256] = make_float4(li[4], li[5], li[6], li[7]);
    }
}

extern "C" void kernel_launch(void* const* d_in, const int* in_sizes, int n_in,
                              void* d_out, int out_size, void* d_ws, size_t ws_size,
                              hipStream_t stream) {
    const float* x     = (const float*)d_in[0];
    const float* theta = (const float*)d_in[1];
    const float* pa    = (const float*)d_in[2];
    const float* pb    = (const float*)d_in[3];
    const float* pc    = (const float*)d_in[4];
    const float* pd    = (const float*)d_in[5];
    float* out = (float*)d_out;
    int N = in_sizes[0];

    BMat Bm = compute_basis();

    int nv = N >> 2;                 // 1,048,576 float4s
    int grid = (nv + 511) / 512;     // 2048 blocks: 8/CU, one residency gen
    cpab_fused<<<grid, 256, 0, stream>>>(x, theta, pa, pb, pc, pd, out, N, Bm);
}

// Round 10
// 14.324 us; speedup vs baseline: 1.3204x; 1.3204x over previous
//
#include <hip/hip_runtime.h>
#include <math.h>

#define NC 5
#define NBASIS (NC + 1)
#define EPSF 1e-10f
#define BIGF 1e10f

typedef float v4f __attribute__((ext_vector_type(4)));

struct BMat { float b[2 * NC][NBASIS]; };

// Reproduce numpy.linalg.svd(L)'s null-space basis (rows nC-1.. of Vt).
// LAPACK dgesdd (M=4 << N=10) LQ path: basis col c = H1 H2 H3 H4 e_{M+c}.
static BMat compute_basis() {
    const int m = NC - 1;      // 4
    const int n = 2 * NC;      // 10
    double A[NC - 1][2 * NC];
    for (int r = 0; r < m; ++r)
        for (int c = 0; c < n; ++c) A[r][c] = 0.0;
    for (int k = 1; k < NC; ++k) {
        double xk = (double)k / (double)NC;
        int i = k - 1;
        A[i][2 * i]     = xk;   A[i][2 * i + 1] = 1.0;
        A[i][2 * i + 2] = -xk;  A[i][2 * i + 3] = -1.0;
    }
    double tau[NC - 1];
    for (int i = 0; i < m; ++i) {
        double alpha = A[i][i];
        double xs = 0.0;
        for (int j = i + 1; j < n; ++j) xs += A[i][j] * A[i][j];
        double xnorm = sqrt(xs);
        if (xnorm == 0.0) { tau[i] = 0.0; continue; }
        double beta = (alpha >= 0.0 ? -1.0 : 1.0) * sqrt(alpha * alpha + xs);
        tau[i] = (beta - alpha) / beta;
        double inv = 1.0 / (alpha - beta);
        for (int j = i + 1; j < n; ++j) A[i][j] *= inv;
        A[i][i] = beta;
        for (int r = i + 1; r < m; ++r) {
            double dot = A[r][i];
            for (int j = i + 1; j < n; ++j) dot += A[r][j] * A[i][j];
            dot *= tau[i];
            A[r][i] -= dot;
            for (int j = i + 1; j < n; ++j) A[r][j] -= dot * A[i][j];
        }
    }
    BMat B;
    for (int c = 0; c < NBASIS; ++c) {
        double v[2 * NC];
        for (int r = 0; r < n; ++r) v[r] = 0.0;
        v[m + c] = 1.0;
        for (int i = m - 1; i >= 0; --i) {
            double dot = v[i];
            for (int j = i + 1; j < n; ++j) dot += A[i][j] * v[j];
            dot *= tau[i];
            v[i] -= dot;
            for (int j = i + 1; j < n; ++j) v[j] -= dot * A[i][j];
        }
        for (int r = 0; r < n; ++r) B.b[r][c] = (float)v[r];
    }
    return B;
}

// Reference-faithful decision logic (verified rounds 2-9) used ONLY to classify
// segment midpoints: kind 0=no-cross, 1=stuck-at-left-knot, 2=cross->jf
__device__ __forceinline__ void classify_pt(
    float ym, int c, float a, float b, float kL, float kR,
    float vL, float vR, const float* tR, int& kind, int& jf)
{
#pragma clang fp contract(off)
    float v = a * ym + b;
    bool pos = (v >= 0.0f);
    float xb = pos ? kR : kL;
    bool at_edge = pos ? (c == NC - 1) : (c == 0);
    float vb = pos ? vR : vL;
    bool vok = fabsf(v) > EPSF;
    float vs = vok ? v : 1.0f;
    float ratio = vb / vs;
    bool aok = fabsf(a) > EPSF;
    float as = aok ? a : 1.0f;
    float t0 = aok ? (logf(ratio > EPSF ? ratio : 1.0f) / as)
                   : ((xb - ym) / vs);
    bool valid = vok && (ratio > EPSF) && (!at_edge);
    if (!valid) t0 = BIGF;
    if (!(t0 < 1.0f)) { kind = 0; jf = c; return; }
    if (!pos)         { kind = 1; jf = c; return; }
    kind = 2;
    int j = c + 1; float T = t0;
    while (j < NC - 1 && (T + tR[j] < 1.0f)) { T += tR[j]; ++j; }
    jf = j;
}

// Fused kernel (R7 structure + 4 float4s/thread). Global x loads issued FIRST;
// build parallelized (phase4: one lane per (cell,segment) = 25 lanes).
// Per segment s=c*5+g: L = log|y-y0|; z = S0 + S1*y + S2*exp(S3*L + S4);
// lj = D0 + D1*L (output affine + ljadd pre-folded).
// Nontemporal stores (R9 A/B: plain stores cost +3.2us via L2 thrash).
__global__ __launch_bounds__(256) void cpab_fused(
    const float* __restrict__ x, const float* __restrict__ theta,
    const float* __restrict__ pa, const float* __restrict__ pb,
    const float* __restrict__ pc, const float* __restrict__ pd,
    float* __restrict__ out, int N, BMat Bm)
{
#pragma clang fp contract(off)
    __shared__ float sA[2 * NC];
    __shared__ float sa[NC], sb[NC], svL[NC], svR[NC], stR[NC], sljR[NC];
    __shared__ float4 sThr[NC];
    __shared__ float4 sS[NC * 5];
    __shared__ float4 sD[NC * 5];
    __shared__ float sAff[4];
    int tid = threadIdx.x;

    // ---- issue all 4 global loads first: latency hides under table build ----
    int nv = N >> 2;
    int base = blockIdx.x * 1024 + tid;      // block tile: 1024 float4s
    bool ok0 = base < nv;
    bool ok1 = (base + 256) < nv;
    bool ok2 = (base + 512) < nv;
    bool ok3 = (base + 768) < nv;
    float4 xv0, xv1, xv2, xv3;
    const float4* x4 = (const float4*)x;
    if (ok0) xv0 = x4[base];
    if (ok1) xv1 = x4[base + 256];
    if (ok2) xv2 = x4[base + 512];
    if (ok3) xv3 = x4[base + 768];

    // ---- phase 1: A = B*theta, affine scalars ----
    if (tid < 2 * NC) {
        float acc = 0.0f;
#pragma unroll
        for (int j = 0; j < NBASIS; ++j) acc += Bm.b[tid][j] * theta[j];
        sA[tid] = acc;
    }
    if (tid == 2 * NC) {
        sAff[0] = pa[0]; sAff[1] = pb[0]; sAff[2] = pc[0]; sAff[3] = pd[0];
    }
    __syncthreads();

    // ---- phase 2: per-cell primitives (bit-identical to ref) ----
    if (tid < NC) {
        int m = tid;
        float a = sA[2 * m], b = sA[2 * m + 1];
        float kL = (float)m / 5.0f, kR = (float)(m + 1) / 5.0f;
        float vL = a * kL + b, vR = a * kR + b;
        bool vok = fabsf(vL) > EPSF;
        float vs = vok ? vL : 1.0f;
        float ratio = vR / vs;
        bool aok = fabsf(a) > EPSF;
        float as = aok ? a : 1.0f;
        float t = aok ? (logf(ratio > EPSF ? ratio : 1.0f) / as)
                      : ((kR - kL) / vs);
        bool valid = vok && (ratio > EPSF) && (m != NC - 1) && (vL >= 0.0f);
        sa[m] = a; sb[m] = b; svL[m] = vL; svR[m] = vR;
        stR[m]  = valid ? t : BIGF;
        sljR[m] = valid ? (a * t) : 0.0f;
    }
    __syncthreads();

    // ---- phase 3: per-cell segment thresholds ----
    if (tid < NC) {
        int c = tid;
        float a = sa[c], b = sb[c];
        float kL = (float)c / 5.0f, kR = (float)(c + 1) / 5.0f;
        float vL = svL[c], vR = svR[c];
        bool aok = fabsf(a) > EPSF;
        float cand[4];
        int ncand = 0;
        if (aok) {
            if (c > 0 && vL < -EPSF) cand[ncand++] = (vL * expf(-a) - b) / a;
            float sum = 0.0f;
            for (int j = c; j <= NC - 2; ++j) {
                if (j > c) {
                    if (stR[j] >= 0.5f * BIGF) break;
                    sum += stR[j];
                    if (sum >= 1.0f) break;
                }
                float tau = 1.0f - sum;
                if (ncand < 4) cand[ncand++] = (vR * expf(-a * tau) - b) / a;
            }
        } else {
            if (c > 0 && b < -EPSF) cand[ncand++] = kL - b;
            if (b > EPSF) {
                float sum = 0.0f;
                for (int j = c; j <= NC - 2; ++j) {
                    if (j > c) {
                        if (stR[j] >= 0.5f * BIGF) break;
                        sum += stR[j];
                        if (sum >= 1.0f) break;
                    }
                    float tau = 1.0f - sum;
                    if (ncand < 4) cand[ncand++] = kR - b * tau;
                }
            }
        }
        for (int i = ncand; i < 4; ++i) cand[i] = 1e30f;
        for (int i = 1; i < 4; ++i) {
            float key = cand[i]; int j = i - 1;
            while (j >= 0 && cand[j] > key) { cand[j + 1] = cand[j]; --j; }
            cand[j + 1] = key;
        }
        sThr[c] = make_float4(cand[0], cand[1], cand[2], cand[3]);
    }
    __syncthreads();

    // ---- phase 4: coefficients, one lane per (cell,segment) = 25 lanes ----
    if (tid < NC * 5) {
        int c = tid / 5, g = tid % 5;
        float a = sa[c], b = sb[c];
        float kL = (float)c / 5.0f, kR = (float)(c + 1) / 5.0f;
        float vL = svL[c], vR = svR[c];
        bool aok = fabsf(a) > EPSF;
        const float* thr = (const float*)&sThr[c];
        float lo = (g == 0) ? -1e30f : thr[g - 1];
        float hi = (g == 4) ?  1e30f : thr[g];
        float lo2 = fmaxf(lo, kL), hi2 = fminf(hi, kR);
        float S0 = 0, S1 = 0, S2 = 0, S3 = 0, S4 = 0, D0 = 0, D1 = 0;
        float aeC = aok ? a : 1e-7f;
        float La  = logf(fabsf(aeC));
        float y0  = -b / aeC;
        if (lo2 < hi2) {
            float ym = 0.5f * (lo2 + hi2);
            int kind, jf;
            classify_pt(ym, c, a, b, kL, kR, vL, vR, stR, kind, jf);
            if (kind == 0) {
                float G = aok ? (expm1f(a) / a) : 1.0f;
                S0 = b * G; S1 = 1.0f + a * G;
                D0 = a;
            } else if (kind == 1) {
                S0 = kL;
                D0 = logf(fabsf(vL)) - La; D1 = -1.0f;
            } else {
                float PTd = 0.0f, PLd = 0.0f;
                for (int m2 = c + 1; m2 < jf; ++m2) { PTd += stR[m2]; PLd += sljR[m2]; }
                float aj  = sa[jf];
                float aeJ = (fabsf(aj) > EPSF) ? aj : 1e-7f;
                float Q   = svL[jf] / aeJ;
                float LVR = logf(vR);       // vR > 0 in cross regime
                S3 = aeJ / aeC;
                S4 = S3 * (La - LVR) - aeJ * PTd;
                S2 = Q * expf(aeJ);
                S0 = (float)jf / 5.0f - Q;  // kL of final cell, minus Q
                D1 = S3 - 1.0f;
                D0 = (1.0f - S3) * LVR + PLd + aj * (1.0f - PTd) + (S3 - 1.0f) * La;
            }
        }
        float affa = sAff[0], affc = sAff[2], affd = sAff[3];
        float ljadd = logf(affa * affc);   // exactly 0 for identity affine
        sS[tid] = make_float4(affc * S0 + affd, affc * S1, affc * S2, S3);
        sD[tid] = make_float4(S4, D0 + ljadd, D1, y0);
    }
    __syncthreads();

    // ---- streaming eval: 16 points/thread, two 8-point halves ----
    float affa = sAff[0], affb = sAff[1];
    v4f* oz = (v4f*)out;
    v4f* ol = (v4f*)(out + N);

#pragma unroll
    for (int h = 0; h < 2; ++h) {
        float4 va = (h == 0) ? xv0 : xv2;
        float4 vb = (h == 0) ? xv1 : xv3;
        bool oa = (h == 0) ? ok0 : ok2;
        bool ob = (h == 0) ? ok1 : ok3;
        int ba = base + (h == 0 ? 0 : 512);
        float xin[8];
        xin[0] = va.x; xin[1] = va.y; xin[2] = va.z; xin[3] = va.w;
        xin[4] = vb.x; xin[5] = vb.y; xin[6] = vb.z; xin[7] = vb.w;
        float zi[8], li[8];
#pragma unroll
        for (int q = 0; q < 8; ++q) {
            float y = affa * xin[q] + affb;        // mul+add order matches ref
            int c = (int)floorf(y * 5.0f);
            c = c < 0 ? 0 : (c > 4 ? 4 : c);
            float4 th = sThr[c];
            int cnt = (y > th.x) + (y > th.y) + (y > th.z) + (y > th.w);
            int s = c * 5 + cnt;
            float4 S = sS[s];
            float4 D = sD[s];
            float L = __logf(fmaxf(fabsf(y - D.w), 1e-37f));
            float E = __expf(fmaf(S.w, L, D.x));
            zi[q] = fmaf(S.z, E, fmaf(S.y, y, S.x));
            li[q] = fmaf(D.z, L, D.y);
        }
        if (oa) {
            v4f z0 = {zi[0], zi[1], zi[2], zi[3]};
            v4f l0 = {li[0], li[1], li[2], li[3]};
            __builtin_nontemporal_store(z0, &oz[ba]);
            __builtin_nontemporal_store(l0, &ol[ba]);
        }
        if (ob) {
            v4f z1 = {zi[4], zi[5], zi[6], zi[7]};
            v4f l1 = {li[4], li[5], li[6], li[7]};
            __builtin_nontemporal_store(z1, &oz[ba + 256]);
            __builtin_nontemporal_store(l1, &ol[ba + 256]);
        }
    }
}

extern "C" void kernel_launch(void* const* d_in, const int* in_sizes, int n_in,
                              void* d_out, int out_size, void* d_ws, size_t ws_size,
                              hipStream_t stream) {
    const float* x     = (const float*)d_in[0];
    const float* theta = (const float*)d_in[1];
    const float* pa    = (const float*)d_in[2];
    const float* pb    = (const float*)d_in[3];
    const float* pc    = (const float*)d_in[4];
    const float* pd    = (const float*)d_in[5];
    float* out = (float*)d_out;
    int N = in_sizes[0];

    BMat Bm = compute_basis();

    int nv = N >> 2;                  // 1,048,576 float4s
    int grid = (nv + 1023) / 1024;    // 1024 blocks: 4/CU, 16 waves/CU
    cpab_fused<<<grid, 256, 0, stream>>>(x, theta, pa, pb, pc, pd, out, N, Bm);
}